// Round 2
// baseline (312.072 us; speedup 1.0000x reference)
//
#include <hip/hip_runtime.h>
#include <hip/hip_bf16.h>
#include <stdint.h>
#include <string.h>
#include <math.h>

// Problem constants
#define B_ 8
#define N_ 512
#define C_ 384
#define HR_ 192          // H*R = 6*32
#define PH_ 16           // PAIR_HIDDEN
#define HEAD_SCALE_ 0.17677669529663687f

// Workspace layout (float offsets)
#define OFF_X   0
#define OFF_Q   (B_*N_*C_)
#define OFF_K   (OFF_Q + B_*N_*HR_)
#define OFF_A   (OFF_K + B_*N_*HR_)
#define OFF_BJ  (OFF_A + B_*N_*PH_)
#define OFF_D   (OFF_BJ + B_*N_*PH_)
#define OFF_CS  (OFF_D + B_*N_)
#define OFF_W   (OFF_CS + 2*B_)
#define OFF_FLAG (OFF_W + 700)               // int: 1 = inputs are bf16, 0 = f32
#define WS_FLOATS (OFF_W + 768)

struct VInit { float v[16]; };

__device__ __forceinline__ float cvt(ushort u) {
  union { uint32_t i; float f; } x; x.i = ((uint32_t)u) << 16; return x.f;
}
__device__ __forceinline__ float cvt(float f) { return f; }

__device__ __forceinline__ float4 ld4v(const ushort* p) {
  ushort4 u = *(const ushort4*)p;
  return make_float4(cvt(u.x), cvt(u.y), cvt(u.z), cvt(u.w));
}
__device__ __forceinline__ float4 ld4v(const float* p) { return *(const float4*)p; }

// ---------------------------------------------------------------------------
// Kernel 0: dtype detection. If Wg1 holds bf16, the low ushort of each dword
// decodes to a sane-magnitude bf16 (N(0,0.3) weights). If it holds f32, the
// low 16 bits are uniform mantissa bits (sane-decode prob ~10%). 128 dwords
// are valid to read under both layouts (512 B <= min(768, 1536) B).
// ---------------------------------------------------------------------------
__global__ void detect_kernel(const uint32_t* __restrict__ wg1, float* __restrict__ ws) {
  if (threadIdx.x == 0 && blockIdx.x == 0) {
    int cnt = 0;
    for (int i = 0; i < 128; ++i) {
      uint32_t d = wg1[i];
      float v = cvt((ushort)(d & 0xFFFFu));
      float av = fabsf(v);
      if (av == 0.0f || (av >= 9.5367431640625e-07f && av <= 32.0f)) ++cnt;
    }
    *(int*)(ws + OFF_FLAG) = (cnt >= 64) ? 1 : 0;
  }
}

// ---------------------------------------------------------------------------
// Weight tables (transposed for uniform scalar loads in score kernel)
// ---------------------------------------------------------------------------
template <typename T>
__device__ void build_tables(const T* Wg1, const T* bg1, const T* Wg2, const T* bg2,
                             const T* Wa1, const T* ba1, const T* Wa2, const T* ba2,
                             const T* apair, const T* ageom, const T* aang, const T* lsc,
                             float* ws, int tid) {
  for (int j = tid; j < 32; j += 256) {
    float* wj = ws + OFF_W + j*16;
    #pragma unroll
    for (int i = 0; i < 12; ++i) wj[i] = cvt(Wg1[i*32 + j]);
    wj[12] = cvt(bg1[j]);
    wj[13] = cvt(Wg2[j]);
    wj[14] = 0.f; wj[15] = 0.f;
  }
  for (int j = tid; j < 16; j += 256) {
    float* wj = ws + OFF_W + 512 + j*8;
    #pragma unroll
    for (int i = 0; i < 6; ++i) wj[i] = cvt(Wa1[i*16 + j]);
    wj[6] = cvt(ba1[j]);
    wj[7] = cvt(Wa2[j]);
  }
  if (tid == 0) {
    ws[OFF_W + 640] = cvt(bg2[0]);
    ws[OFF_W + 641] = cvt(ba2[0]);
    ws[OFF_W + 642] = fmaxf(cvt(apair[0]), 0.f);
    ws[OFF_W + 643] = fmaxf(cvt(ageom[0]), 0.f);
    ws[OFF_W + 644] = fmaxf(cvt(aang[0]), 0.f);
    ws[OFF_W + 645] = fmaxf(cvt(lsc[0]), 0.01f);
  }
}

// ---------------------------------------------------------------------------
// Kernel A: per-batch principal orientation (power iteration) + weight tables
// ---------------------------------------------------------------------------
__global__ __launch_bounds__(256) void prep_kernel(
    const void* __restrict__ xy,
    const void* __restrict__ Wg1, const void* __restrict__ bg1,
    const void* __restrict__ Wg2, const void* __restrict__ bg2,
    const void* __restrict__ Wa1, const void* __restrict__ ba1,
    const void* __restrict__ Wa2, const void* __restrict__ ba2,
    const void* __restrict__ apair, const void* __restrict__ ageom,
    const void* __restrict__ aang, const void* __restrict__ lsc,
    float* __restrict__ ws, VInit vi)
{
  const int b = blockIdx.x, tid = threadIdx.x;
  const int bf = *(volatile const int*)(ws + OFF_FLAG);
  __shared__ float sxy[N_*2];
  __shared__ float red[256][4];

  if (bf) {
    const ushort* p = (const ushort*)xy + b*N_*2;
    for (int i = tid; i < N_*2; i += 256) sxy[i] = cvt(p[i]);
  } else {
    const float* p = (const float*)xy + b*N_*2;
    for (int i = tid; i < N_*2; i += 256) sxy[i] = p[i];
  }
  __syncthreads();

  // pass 1: mean
  float sy = 0.f, sx = 0.f;
  for (int i = tid; i < N_; i += 256) { sy += sxy[2*i]; sx += sxy[2*i+1]; }
  red[tid][0] = sy; red[tid][1] = sx;
  __syncthreads();
  for (int s = 128; s > 0; s >>= 1) {
    if (tid < s) { red[tid][0] += red[tid+s][0]; red[tid][1] += red[tid+s][1]; }
    __syncthreads();
  }
  const float my = red[0][0] / 512.0f;
  const float mx = red[0][1] / 512.0f;
  __syncthreads();

  // pass 2: covariance
  float c00 = 0.f, c01 = 0.f, c11 = 0.f;
  for (int i = tid; i < N_; i += 256) {
    float y = sxy[2*i] - my;
    float x = sxy[2*i+1] - mx;
    c00 += y*y; c01 += y*x; c11 += x*x;
  }
  red[tid][0] = c00; red[tid][1] = c01; red[tid][2] = c11;
  __syncthreads();
  for (int s = 128; s > 0; s >>= 1) {
    if (tid < s) {
      red[tid][0] += red[tid+s][0];
      red[tid][1] += red[tid+s][1];
      red[tid][2] += red[tid+s][2];
    }
    __syncthreads();
  }
  if (tid == 0) {
    float C00 = red[0][0] / 512.0f, C01 = red[0][1] / 512.0f, C11 = red[0][2] / 512.0f;
    float v0 = vi.v[2*b], v1 = vi.v[2*b + 1];
    float nr = sqrtf(v0*v0 + v1*v1) + 1e-8f; v0 /= nr; v1 /= nr;
    for (int it = 0; it < 5; ++it) {
      float w0 = C00*v0 + C01*v1;
      float w1 = C01*v0 + C11*v1;
      nr = sqrtf(w0*w0 + w1*w1) + 1e-8f;
      v0 = w0/nr; v1 = w1/nr;
    }
    float h = sqrtf(v0*v0 + v1*v1);
    ws[OFF_CS + 2*b + 0] = v0 / h;   // cos(theta0)
    ws[OFF_CS + 2*b + 1] = v1 / h;   // sin(theta0)
  }

  if (b == 0) {
    if (bf) build_tables((const ushort*)Wg1, (const ushort*)bg1, (const ushort*)Wg2, (const ushort*)bg2,
                         (const ushort*)Wa1, (const ushort*)ba1, (const ushort*)Wa2, (const ushort*)ba2,
                         (const ushort*)apair, (const ushort*)ageom, (const ushort*)aang, (const ushort*)lsc,
                         ws, tid);
    else    build_tables((const float*)Wg1, (const float*)bg1, (const float*)Wg2, (const float*)bg2,
                         (const float*)Wa1, (const float*)ba1, (const float*)Wa2, (const float*)ba2,
                         (const float*)apair, (const float*)ageom, (const float*)aang, (const float*)lsc,
                         ws, tid);
  }
}

// ---------------------------------------------------------------------------
// Kernel B: fold vertices -> x (f32)
// ---------------------------------------------------------------------------
template <typename T>
__device__ __forceinline__ void fold_body(const T* feats, float* ws, int idx) {
  const int c4 = idx % 96;
  const int bn = idx / 96;
  const int n = bn & (N_ - 1), b = bn >> 9;
  const T* r1 = feats + ((size_t)(b*(2*N_+1) + 1 + 2*n))*C_ + c4*4;
  float4 a = ld4v(r1);
  float4 c = ld4v(r1 + C_);
  float4 o;
  o.x = 0.5f*(a.x + c.x); o.y = 0.5f*(a.y + c.y);
  o.z = 0.5f*(a.z + c.z); o.w = 0.5f*(a.w + c.w);
  *(float4*)(ws + OFF_X + (size_t)idx*4) = o;
}

__global__ __launch_bounds__(256) void fold_kernel(const void* __restrict__ feats,
                                                   float* __restrict__ ws) {
  const int idx = blockIdx.x * 256 + threadIdx.x;
  const int bf = *(volatile const int*)(ws + OFF_FLAG);
  if (bf) fold_body((const ushort*)feats, ws, idx);
  else    fold_body((const float*)feats, ws, idx);
}

// ---------------------------------------------------------------------------
// Kernel C: projections Q, K, a_i, b_j, d
// ---------------------------------------------------------------------------
template <typename T>
__device__ void proj_body(const T* Wq, const T* Wk, const T* Wpi, const T* bpi,
                          const T* Wpj, const T* bpj, const T* Wd, const T* bd,
                          float* ws, int b, int r0, int tid) {
  const float* xr = ws + OFF_X + ((size_t)(b*N_) + r0) * C_;   // 8 rows, uniform

  for (int j = tid; j < 384; j += 256) {
    const T* W; int col; float* dst;
    if (j < 192) { W = Wq; col = j;       dst = ws + OFF_Q + ((size_t)(b*N_) + r0)*HR_ + col; }
    else         { W = Wk; col = j - 192; dst = ws + OFF_K + ((size_t)(b*N_) + r0)*HR_ + col; }
    float acc[8] = {0,0,0,0,0,0,0,0};
    for (int c4 = 0; c4 < 96; ++c4) {
      float w0 = cvt(W[(c4*4 + 0)*HR_ + col]);
      float w1 = cvt(W[(c4*4 + 1)*HR_ + col]);
      float w2 = cvt(W[(c4*4 + 2)*HR_ + col]);
      float w3 = cvt(W[(c4*4 + 3)*HR_ + col]);
      #pragma unroll
      for (int r = 0; r < 8; ++r) {
        float4 xv = *(const float4*)(xr + r*C_ + c4*4);
        acc[r] = fmaf(xv.x, w0, fmaf(xv.y, w1, fmaf(xv.z, w2, fmaf(xv.w, w3, acc[r]))));
      }
    }
    #pragma unroll
    for (int r = 0; r < 8; ++r) dst[r*HR_] = acc[r];
  }

  for (int j = tid; j < 33; j += 256) {
    const T* W; int col, ostr, dstr; float bias; float* dst; bool rl;
    if (j < 16)      { W = Wpi; col = j;      ostr = 16; bias = cvt(bpi[col]); dst = ws + OFF_A  + ((size_t)(b*N_) + r0)*PH_ + col; dstr = PH_; rl = true; }
    else if (j < 32) { W = Wpj; col = j - 16; ostr = 16; bias = cvt(bpj[col]); dst = ws + OFF_BJ + ((size_t)(b*N_) + r0)*PH_ + col; dstr = PH_; rl = true; }
    else             { W = Wd;  col = 0;      ostr = 1;  bias = cvt(bd[0]);    dst = ws + OFF_D  + (size_t)(b*N_) + r0;             dstr = 1;   rl = false; }
    float acc[8] = {0,0,0,0,0,0,0,0};
    for (int c = 0; c < C_; ++c) {
      float w = cvt(W[c*ostr + col]);
      #pragma unroll
      for (int r = 0; r < 8; ++r) acc[r] = fmaf(xr[r*C_ + c], w, acc[r]);
    }
    #pragma unroll
    for (int r = 0; r < 8; ++r) {
      float v = acc[r] + bias;
      if (rl) v = fmaxf(v, 0.f);
      dst[r*dstr] = v;
    }
  }
}

__global__ __launch_bounds__(256) void proj_kernel(
    const void* __restrict__ Wq, const void* __restrict__ Wk,
    const void* __restrict__ Wpi, const void* __restrict__ bpi,
    const void* __restrict__ Wpj, const void* __restrict__ bpj,
    const void* __restrict__ Wd,  const void* __restrict__ bd,
    float* __restrict__ ws)
{
  const int tid = threadIdx.x;
  const int b = blockIdx.x >> 6;
  const int r0 = (blockIdx.x & 63) * 8;
  const int bf = *(volatile const int*)(ws + OFF_FLAG);
  if (bf) proj_body((const ushort*)Wq, (const ushort*)Wk, (const ushort*)Wpi, (const ushort*)bpi,
                    (const ushort*)Wpj, (const ushort*)bpj, (const ushort*)Wd, (const ushort*)bd,
                    ws, b, r0, tid);
  else    proj_body((const float*)Wq, (const float*)Wk, (const float*)Wpi, (const float*)bpi,
                    (const float*)Wpj, (const float*)bpj, (const float*)Wd, (const float*)bd,
                    ws, b, r0, tid);
}

// ---------------------------------------------------------------------------
// Kernel D: fused score assembly
// ---------------------------------------------------------------------------
__global__ __launch_bounds__(256, 2) void score_kernel(
    const void* __restrict__ xy, const float* __restrict__ ws,
    void* __restrict__ out)
{
  const int b  = blockIdx.z;
  const int n0 = blockIdx.y * 32, m0 = blockIdx.x * 32;
  const int tid = threadIdx.x;
  const int bf = *(volatile const int*)(ws + OFF_FLAG);

  __shared__ float Qt[32][196];   // pad 192->196: rows land on distinct banks
  __shared__ float Kt[32][196];
  __shared__ float At[32][20];    // pad 16->20
  __shared__ float Bt[32][20];
  __shared__ float xyn[32][2], xym[32][2], dn[32];

  const float* Qg = ws + OFF_Q + ((size_t)(b*N_) + n0) * HR_;
  const float* Kg = ws + OFF_K + ((size_t)(b*N_) + m0) * HR_;
  for (int i = tid; i < 1536; i += 256) {
    int row = i / 48, c = (i % 48) * 4;
    *(float4*)&Qt[row][c] = *(const float4*)(Qg + row*HR_ + c);
    *(float4*)&Kt[row][c] = *(const float4*)(Kg + row*HR_ + c);
  }
  const float* Ag = ws + OFF_A  + ((size_t)(b*N_) + n0) * PH_;
  const float* Bg = ws + OFF_BJ + ((size_t)(b*N_) + m0) * PH_;
  for (int i = tid; i < 128; i += 256) {
    int row = i / 4, c = (i % 4) * 4;
    *(float4*)&At[row][c] = *(const float4*)(Ag + row*PH_ + c);
    *(float4*)&Bt[row][c] = *(const float4*)(Bg + row*PH_ + c);
  }
  if (bf) {
    const ushort* p = (const ushort*)xy;
    if (tid < 32) {
      xyn[tid][0] = cvt(p[((b*N_) + n0 + tid)*2 + 0]);
      xyn[tid][1] = cvt(p[((b*N_) + n0 + tid)*2 + 1]);
      xym[tid][0] = cvt(p[((b*N_) + m0 + tid)*2 + 0]);
      xym[tid][1] = cvt(p[((b*N_) + m0 + tid)*2 + 1]);
      dn[tid] = ws[OFF_D + b*N_ + n0 + tid];
    }
  } else {
    const float* p = (const float*)xy;
    if (tid < 32) {
      xyn[tid][0] = p[((b*N_) + n0 + tid)*2 + 0];
      xyn[tid][1] = p[((b*N_) + n0 + tid)*2 + 1];
      xym[tid][0] = p[((b*N_) + m0 + tid)*2 + 0];
      xym[tid][1] = p[((b*N_) + m0 + tid)*2 + 1];
      dn[tid] = ws[OFF_D + b*N_ + n0 + tid];
    }
  }
  __syncthreads();

  const float c0 = ws[OFF_CS + 2*b], s0 = ws[OFF_CS + 2*b + 1];
  const float* wsm = ws + OFF_W;
  const float bg2v = wsm[640], ba2v = wsm[641];
  const float ap = wsm[642], ag = wsm[643], aa = wsm[644], ls = wsm[645];

  const int nl = tid >> 3, mg = tid & 7;   // thread: row nl, 4 cols mg+8p

  float accQ[4] = {0,0,0,0}, accP[4] = {0,0,0,0};
  #pragma unroll 4
  for (int c = 0; c < HR_; c += 4) {
    float4 q = *(const float4*)&Qt[nl][c];
    #pragma unroll
    for (int p = 0; p < 4; ++p) {
      float4 k = *(const float4*)&Kt[mg + 8*p][c];
      accQ[p] = fmaf(q.x,k.x, fmaf(q.y,k.y, fmaf(q.z,k.z, fmaf(q.w,k.w, accQ[p]))));
    }
  }
  #pragma unroll
  for (int c = 0; c < PH_; c += 4) {
    float4 a = *(const float4*)&At[nl][c];
    #pragma unroll
    for (int p = 0; p < 4; ++p) {
      float4 v = *(const float4*)&Bt[mg + 8*p][c];
      accP[p] = fmaf(a.x,v.x, fmaf(a.y,v.y, fmaf(a.z,v.z, fmaf(a.w,v.w, accP[p]))));
    }
  }

  // geometry features (rotation identities; no atan2/sin/cos needed)
  const float STEP  = 1.41421354f / 7.0f;
  const float GAMMA = 1.0f / (2.0f*STEP*STEP + 1e-8f);
  const float yn = xyn[nl][0], xn = xyn[nl][1];
  float DY[4], DX[4], C1[4], S1[4], C2[4], S2[4], C4v[4], S4[4], PHI[4][8];
  #pragma unroll
  for (int p = 0; p < 4; ++p) {
    int ml = mg + 8*p;
    float dy = yn - xym[ml][0], dx = xn - xym[ml][1];
    DY[p] = dy; DX[p] = dx;
    float h2 = fmaf(dx, dx, dy*dy);
    float r = sqrtf(h2 + 1e-8f);
    float ct, st;
    if (h2 > 0.f) { float ih = 1.0f / sqrtf(h2); ct = dx*ih; st = dy*ih; }
    else          { ct = 1.f; st = 0.f; }             // atan2(0,0)=0
    float c1 = ct*c0 + st*s0;                         // cos(theta - theta0)
    float s1 = st*c0 - ct*s0;                         // sin(theta - theta0)
    C1[p] = c1; S1[p] = s1;
    float c2 = c1*c1 - s1*s1, s2 = 2.f*c1*s1;
    C2[p] = c2; S2[p] = s2;
    C4v[p] = c2*c2 - s2*s2; S4[p] = 2.f*c2*s2;
    #pragma unroll
    for (int k = 0; k < 8; ++k) {
      float d = r - (float)k * STEP;
      PHI[p][k] = __expf(-GAMMA * d * d);
    }
  }

  // G MLP: 12 -> 32 -> 1 (weights via uniform scalar loads)
  float g[4] = {0,0,0,0};
  #pragma unroll 4
  for (int j = 0; j < 32; ++j) {
    const float* wj = wsm + j*16;
    #pragma unroll
    for (int p = 0; p < 4; ++p) {
      float h = fmaf(DY[p], wj[0], fmaf(DX[p], wj[1], wj[12]));
      #pragma unroll
      for (int k = 0; k < 8; ++k) h = fmaf(PHI[p][k], wj[2+k], h);
      h = fmaf(C1[p], wj[10], fmaf(S1[p], wj[11], h));
      g[p] = fmaf(fmaxf(h, 0.f), wj[13], g[p]);
    }
  }

  // angle MLP: 6 -> 16 -> 1
  float hb[4] = {0,0,0,0};
  #pragma unroll 4
  for (int j = 0; j < 16; ++j) {
    const float* wj = wsm + 512 + j*8;
    #pragma unroll
    for (int p = 0; p < 4; ++p) {
      float h = fmaf(C1[p],  wj[0], fmaf(S1[p], wj[1], wj[6]));
      h = fmaf(C2[p],  wj[2], fmaf(S2[p], wj[3], h));
      h = fmaf(C4v[p], wj[4], fmaf(S4[p], wj[5], h));
      hb[p] = fmaf(fmaxf(h, 0.f), wj[7], hb[p]);
    }
  }

  const int n_g = n0 + nl;
  #pragma unroll
  for (int p = 0; p < 4; ++p) {
    const int m_g = m0 + mg + 8*p;
    float S = HEAD_SCALE_*accQ[p] + ap*accP[p] + ag*(g[p] + bg2v) + aa*(hb[p] + ba2v);
    if (n_g == m_g) S += dn[nl];
    S *= ls;
    const size_t oi = ((size_t)(b*N_) + n_g)*N_ + m_g;
    if (bf) ((__hip_bfloat16*)out)[oi] = __float2bfloat16(S);
    else    ((float*)out)[oi] = S;
  }
}

// ---------------------------------------------------------------------------
// Host: replicate jax.random.normal(key(42), (8,2,1)) — threefry2x32
// (partitionable mode) + XLA/Giles f32 erfinv.
// ---------------------------------------------------------------------------
static inline uint32_t rotl32(uint32_t x, int d) { return (x << d) | (x >> (32 - d)); }

static void threefry2x32_host(uint32_t k0, uint32_t k1, uint32_t& x0, uint32_t& x1) {
  const uint32_t ks0 = k0, ks1 = k1, ks2 = k0 ^ k1 ^ 0x1BD11BDAu;
  static const int R[2][4] = {{13,15,26,6},{17,29,16,24}};
  x0 += ks0; x1 += ks1;
  const uint32_t ks[3] = {ks0, ks1, ks2};
  for (int i = 0; i < 5; ++i) {
    const int* r = R[i & 1];
    for (int j = 0; j < 4; ++j) { x0 += x1; x1 = rotl32(x1, r[j]); x1 ^= x0; }
    x0 += ks[(i + 1) % 3];
    x1 += ks[(i + 2) % 3] + (uint32_t)(i + 1);
  }
}

static float erfinv_host(float x) {
  float w = -log1pf(-x * x);
  float p;
  if (w < 5.0f) {
    w = w - 2.5f;
    p = 2.81022636e-08f;
    p = fmaf(p, w, 3.43273939e-07f);
    p = fmaf(p, w, -3.5233877e-06f);
    p = fmaf(p, w, -4.39150654e-06f);
    p = fmaf(p, w, 0.00021858087f);
    p = fmaf(p, w, -0.00125372503f);
    p = fmaf(p, w, -0.00417768164f);
    p = fmaf(p, w, 0.246640727f);
    p = fmaf(p, w, 1.50140941f);
  } else {
    w = sqrtf(w) - 3.0f;
    p = -0.000200214257f;
    p = fmaf(p, w, 0.000100950558f);
    p = fmaf(p, w, 0.00134934322f);
    p = fmaf(p, w, -0.00367342844f);
    p = fmaf(p, w, 0.00573950773f);
    p = fmaf(p, w, -0.0076224613f);
    p = fmaf(p, w, 0.00943887047f);
    p = fmaf(p, w, 1.00167406f);
    p = fmaf(p, w, 2.83297682f);
  }
  return p * x;
}

static VInit make_vinit() {
  VInit vi;
  for (int i = 0; i < 16; ++i) {
    uint32_t o0 = 0u, o1 = (uint32_t)i;
    threefry2x32_host(0u, 42u, o0, o1);
    uint32_t bits = o0 ^ o1;
    uint32_t fb = (bits >> 9) | 0x3f800000u;
    float f; memcpy(&f, &fb, 4); f -= 1.0f;
    const float lo = -0.99999994f;
    float u = f * 2.0f + lo;
    if (u < lo) u = lo;
    vi.v[i] = 1.41421354f * erfinv_host(u);
  }
  return vi;
}

// ---------------------------------------------------------------------------
extern "C" void kernel_launch(void* const* d_in, const int* in_sizes, int n_in,
                              void* d_out, int out_size, void* d_ws, size_t ws_size,
                              hipStream_t stream) {
  (void)in_sizes; (void)n_in; (void)out_size;
  if (ws_size < (size_t)WS_FLOATS * sizeof(float)) return;

  const void* feats = d_in[0];
  const void* xy    = d_in[1];
  const void* Wq    = d_in[2];
  const void* Wk    = d_in[3];
  const void* Wpi   = d_in[4];
  const void* bpi   = d_in[5];
  const void* Wpj   = d_in[6];
  const void* bpj   = d_in[7];
  const void* apair = d_in[8];
  const void* Wg1   = d_in[9];
  const void* bg1   = d_in[10];
  const void* bg2w  = d_in[11];  // Wg2
  const void* bg2b  = d_in[12];  // bg2
  const void* ageom = d_in[13];
  const void* Wa1   = d_in[14];
  const void* ba1   = d_in[15];
  const void* Wa2   = d_in[16];
  const void* ba2   = d_in[17];
  const void* aang  = d_in[18];
  const void* Wd    = d_in[19];
  const void* bd    = d_in[20];
  const void* lsc   = d_in[21];
  float* ws = (float*)d_ws;

  VInit vi = make_vinit();

  hipLaunchKernelGGL(detect_kernel, dim3(1), dim3(64), 0, stream,
      (const uint32_t*)Wg1, ws);
  hipLaunchKernelGGL(prep_kernel, dim3(B_), dim3(256), 0, stream,
      xy, Wg1, bg1, bg2w, bg2b, Wa1, ba1, Wa2, ba2, apair, ageom, aang, lsc, ws, vi);
  hipLaunchKernelGGL(fold_kernel, dim3(1536), dim3(256), 0, stream, feats, ws);
  hipLaunchKernelGGL(proj_kernel, dim3(512), dim3(256), 0, stream,
      Wq, Wk, Wpi, bpi, Wpj, bpj, Wd, bd, ws);
  hipLaunchKernelGGL(score_kernel, dim3(16, 16, B_), dim3(256), 0, stream,
      xy, ws, d_out);
}